// Round 3
// baseline (56.820 us; speedup 1.0000x reference)
//
#include <hip/hip_runtime.h>
#include <math.h>

#define B_ 8
#define C_ 256
#define C2_ 512
#define DK_ 32
#define HW_ 2304

// ws layout (floats):
#define WS_WQ   0        // wq_eff [8][256]
#define WS_VG   2048     // vg     [8][256]
#define WS_QB   4096     // qb     [8]
#define WS_S    4352     // s      [8][2304]

__device__ __forceinline__ float gelu_exact(float x) {
    return 0.5f * x * (1.0f + erff(x * 0.70710678118654752f));
}

// One block = (b, tile). Redundantly computes the whole text path for batch b
// (tiny), then writes its 32-row tile of vg. tile==0 also computes kg -> wq_eff, qb.
__global__ __launch_bounds__(512) void k_prep(
    const float* __restrict__ text,
    const float* __restrict__ Wg1,  const float* __restrict__ bg1,
    const float* __restrict__ ln_g, const float* __restrict__ ln_b,
    const float* __restrict__ Wg2,  const float* __restrict__ bg2,
    const float* __restrict__ Wq,   const float* __restrict__ bq,
    const float* __restrict__ Wk,   const float* __restrict__ Wv,
    float* __restrict__ ws)
{
    const int b = blockIdx.x >> 3;
    const int tile = blockIdx.x & 7;          // 8 tiles of 32 vg rows
    const int tid = threadIdx.x;              // 512 threads

    __shared__ float tx[C_];
    __shared__ __align__(16) float tsh[C2_];
    __shared__ __align__(16) float gvs[C_];
    __shared__ float part2[2][C_];
    __shared__ float r1[8], r2[8];
    __shared__ float kg[DK_];

    if (tid < C_) tx[tid] = text[b * C_ + tid];
    __syncthreads();

    // stage A: t_pre col tid = text·Wg1[:,tid] + bg1[tid]
    float acc = bg1[tid];
    #pragma unroll 8
    for (int c = 0; c < C_; ++c)
        acc += tx[c] * Wg1[(size_t)c * C2_ + tid];

    // LayerNorm stats over the 512 values (one per thread)
    float s1 = acc, s2 = acc * acc;
    for (int o = 32; o; o >>= 1) {
        s1 += __shfl_down(s1, o);
        s2 += __shfl_down(s2, o);
    }
    if ((tid & 63) == 0) { r1[tid >> 6] = s1; r2[tid >> 6] = s2; }
    __syncthreads();
    s1 = 0.f; s2 = 0.f;
    #pragma unroll
    for (int u = 0; u < 8; ++u) { s1 += r1[u]; s2 += r2[u]; }
    const float mu = s1 * (1.0f / 512.0f);
    const float rstd = rsqrtf(s2 * (1.0f / 512.0f) - mu * mu + 1e-5f);
    tsh[tid] = gelu_exact((acc - mu) * rstd * ln_g[tid] + ln_b[tid]);
    __syncthreads();

    // stage B: gv col (tid&255), split K over two halves of the block
    {
        const int col = tid & 255, half = tid >> 8;
        float g = 0.f;
        const float* wcol = Wg2 + (size_t)(half * 256) * C_ + col;
        #pragma unroll 8
        for (int j = 0; j < 256; ++j)
            g += tsh[half * 256 + j] * wcol[(size_t)j * C_];
        part2[half][col] = g;
    }
    __syncthreads();
    if (tid < C_) gvs[tid] = part2[0][tid] + part2[1][tid] + bg2[tid];
    __syncthreads();

    // stage C: vg rows tile*32..tile*32+31  (32 rows x 16 lanes, float4)
    const int o = tid >> 4, sub = tid & 15;
    const float4* gv4 = (const float4*)gvs + sub * 4;
    {
        const float4* wrow = (const float4*)(Wv + (size_t)(tile * 32 + o) * C_) + sub * 4;
        float a = 0.f;
        #pragma unroll
        for (int k4 = 0; k4 < 4; ++k4) {
            float4 w4 = wrow[k4], g4 = gv4[k4];
            a += w4.x * g4.x + w4.y * g4.y + w4.z * g4.z + w4.w * g4.w;
        }
        a += __shfl_xor(a, 1);
        a += __shfl_xor(a, 2);
        a += __shfl_xor(a, 4);
        a += __shfl_xor(a, 8);
        if (sub == 0) ws[WS_VG + b * C_ + tile * 32 + o] = a;
    }

    if (tile == 0) {
        // kg[d] = Wk[d,:]·gv  (same 32x16 decomposition)
        const float4* wrow = (const float4*)(Wk + (size_t)o * C_) + sub * 4;
        float a = 0.f;
        #pragma unroll
        for (int k4 = 0; k4 < 4; ++k4) {
            float4 w4 = wrow[k4], g4 = gv4[k4];
            a += w4.x * g4.x + w4.y * g4.y + w4.z * g4.z + w4.w * g4.w;
        }
        a += __shfl_xor(a, 1);
        a += __shfl_xor(a, 2);
        a += __shfl_xor(a, 4);
        a += __shfl_xor(a, 8);
        if (sub == 0) kg[o] = a;
        __syncthreads();
        if (tid < C_) {
            float w = 0.f;
            #pragma unroll
            for (int d = 0; d < DK_; ++d) w += kg[d] * Wq[(size_t)d * C_ + tid];
            ws[WS_WQ + b * C_ + tid] = w;
        }
        if (tid == 0) {
            float q = 0.f;
            #pragma unroll
            for (int d = 0; d < DK_; ++d) q += kg[d] * bq[d];
            ws[WS_QB + b] = q;
        }
    }
}

// One block = (b, 32-pixel tile): a[i] = wq·img[b,:,i] + qb, then
// s[i] = sum_j l[j]*e(i,j) / sum_j e(i,j),  e = exp(a[i]*l[j] - mx).
__global__ __launch_bounds__(256) void k_as(
    const float* __restrict__ img, const float* __restrict__ l,
    float* __restrict__ ws)
{
    const int blk = blockIdx.x;          // 576 = 8 b * 72 tiles
    const int b = blk / 72;
    const int i0 = (blk % 72) * 32;
    const int tid = threadIdx.x;

    __shared__ float lsh[HW_];
    __shared__ float wq[C_];
    __shared__ float part[8][32];
    __shared__ float aa[32];
    __shared__ float redmn[4], redmx[4];

    wq[tid] = ws[WS_WQ + b * C_ + tid];
    float mn = 1e30f, mx = -1e30f;
    #pragma unroll
    for (int j = tid; j < HW_; j += 256) {
        float v = l[j];
        lsh[j] = v;
        mn = fminf(mn, v); mx = fmaxf(mx, v);
    }
    for (int o = 32; o; o >>= 1) {
        mn = fminf(mn, __shfl_down(mn, o));
        mx = fmaxf(mx, __shfl_down(mx, o));
    }
    if ((tid & 63) == 0) { redmn[tid >> 6] = mn; redmx[tid >> 6] = mx; }
    __syncthreads();
    const float lmin = fminf(fminf(redmn[0], redmn[1]), fminf(redmn[2], redmn[3]));
    const float lmax = fmaxf(fmaxf(redmx[0], redmx[1]), fmaxf(redmx[2], redmx[3]));

    // a phase: 8 channel-groups x 32 pixels
    {
        const int pix = tid & 31, sub = tid >> 5;
        const float* x = img + ((size_t)b * C_ + sub * 32) * HW_ + i0 + pix;
        float acc = 0.f;
        #pragma unroll 8
        for (int k = 0; k < 32; ++k)
            acc += wq[sub * 32 + k] * x[(size_t)k * HW_];
        part[sub][pix] = acc;
    }
    __syncthreads();
    if (tid < 32) {
        float a = ws[WS_QB + b];
        #pragma unroll
        for (int u = 0; u < 8; ++u) a += part[u][tid];
        aa[tid] = a;
    }
    __syncthreads();

    // s phase: 32 pixels x 8 lanes
    const int spix = tid >> 3, ssub = tid & 7;
    const float m = aa[spix];
    const float mxv = (m >= 0.f) ? m * lmax : m * lmin;
    float se = 0.f, sle = 0.f;
    #pragma unroll 4
    for (int j = ssub; j < HW_; j += 8) {
        float lj = lsh[j];
        float e = __expf(m * lj - mxv);
        se += e;
        sle += e * lj;
    }
    se += __shfl_xor(se, 1);  sle += __shfl_xor(sle, 1);
    se += __shfl_xor(se, 2);  sle += __shfl_xor(sle, 2);
    se += __shfl_xor(se, 4);  sle += __shfl_xor(sle, 4);
    if (ssub == 0) ws[WS_S + b * HW_ + i0 + spix] = sle / se;
}

// out[b,c,i] = img[b,c,i] + gamma*(vg[b,c]*s[b,i] + bv[c])
__global__ __launch_bounds__(256) void k_out(
    const float* __restrict__ img, const float* __restrict__ bv,
    const float* __restrict__ gamma, const float* __restrict__ ws,
    float* __restrict__ out)
{
    const float g = gamma[0];
    const size_t idx = (size_t)blockIdx.x * 256 + threadIdx.x;  // float4 index
    const size_t flat = idx * 4;
    const int b = (int)(flat / (C_ * HW_));
    const int rem = (int)(flat % (C_ * HW_));
    const int c = rem / HW_;
    const int i = rem % HW_;

    const float4 im = *(const float4*)(img + flat);
    const float4 s4 = *(const float4*)(ws + WS_S + b * HW_ + i);
    const float vgc = ws[WS_VG + b * C_ + c];
    const float bvc = bv[c];
    float4 o;
    o.x = im.x + g * (vgc * s4.x + bvc);
    o.y = im.y + g * (vgc * s4.y + bvc);
    o.z = im.z + g * (vgc * s4.z + bvc);
    o.w = im.w + g * (vgc * s4.w + bvc);
    *(float4*)(out + flat) = o;
}

extern "C" void kernel_launch(void* const* d_in, const int* in_sizes, int n_in,
                              void* d_out, int out_size, void* d_ws, size_t ws_size,
                              hipStream_t stream) {
    const float* img   = (const float*)d_in[0];
    const float* text  = (const float*)d_in[1];
    const float* l     = (const float*)d_in[2];
    const float* Wg1   = (const float*)d_in[3];
    const float* bg1   = (const float*)d_in[4];
    const float* ln_g  = (const float*)d_in[5];
    const float* ln_b  = (const float*)d_in[6];
    const float* Wg2   = (const float*)d_in[7];
    const float* bg2   = (const float*)d_in[8];
    const float* Wq    = (const float*)d_in[9];
    const float* bq    = (const float*)d_in[10];
    const float* Wk    = (const float*)d_in[11];
    // bk (d_in[12]) cancels in the softmax — unused
    const float* Wv    = (const float*)d_in[13];
    const float* bv    = (const float*)d_in[14];
    const float* gamma = (const float*)d_in[15];
    float* out = (float*)d_out;
    float* ws  = (float*)d_ws;

    k_prep<<<64, 512, 0, stream>>>(text, Wg1, bg1, ln_g, ln_b, Wg2, bg2,
                                   Wq, bq, Wk, Wv, ws);
    k_as<<<576, 256, 0, stream>>>(img, l, ws);
    k_out<<<(size_t)B_ * C_ * HW_ / 4 / 256, 256, 0, stream>>>(img, bv, gamma, ws, out);
}

// Round 4
// 52.468 us; speedup vs baseline: 1.0829x; 1.0829x over previous
//
#include <hip/hip_runtime.h>
#include <math.h>

#define B_ 8
#define C_ 256
#define C2_ 512
#define DK_ 32
#define HW_ 2304

// ws layout (floats):
#define WS_WQ   0        // wq_eff [8][256]
#define WS_VG   2048     // vg     [8][256]
#define WS_QB   4096     // qb     [8]

__device__ __forceinline__ float gelu_exact(float x) {
    return 0.5f * x * (1.0f + erff(x * 0.70710678118654752f));
}

// One block = (b, tile). Redundantly computes the whole text path for batch b
// (tiny), then writes its 32-row tile of vg. tile==0 also computes kg -> wq_eff, qb.
__global__ __launch_bounds__(512) void k_prep(
    const float* __restrict__ text,
    const float* __restrict__ Wg1,  const float* __restrict__ bg1,
    const float* __restrict__ ln_g, const float* __restrict__ ln_b,
    const float* __restrict__ Wg2,  const float* __restrict__ bg2,
    const float* __restrict__ Wq,   const float* __restrict__ bq,
    const float* __restrict__ Wk,   const float* __restrict__ Wv,
    float* __restrict__ ws)
{
    const int b = blockIdx.x >> 3;
    const int tile = blockIdx.x & 7;          // 8 tiles of 32 vg rows
    const int tid = threadIdx.x;              // 512 threads

    __shared__ float tx[C_];
    __shared__ __align__(16) float tsh[C2_];
    __shared__ __align__(16) float gvs[C_];
    __shared__ float part2[2][C_];
    __shared__ float r1[8], r2[8];
    __shared__ float kg[DK_];

    if (tid < C_) tx[tid] = text[b * C_ + tid];
    __syncthreads();

    // stage A: t_pre col tid = text·Wg1[:,tid] + bg1[tid]
    float acc = bg1[tid];
    #pragma unroll 8
    for (int c = 0; c < C_; ++c)
        acc += tx[c] * Wg1[(size_t)c * C2_ + tid];

    // LayerNorm stats over the 512 values (one per thread)
    float s1 = acc, s2 = acc * acc;
    for (int o = 32; o; o >>= 1) {
        s1 += __shfl_down(s1, o);
        s2 += __shfl_down(s2, o);
    }
    if ((tid & 63) == 0) { r1[tid >> 6] = s1; r2[tid >> 6] = s2; }
    __syncthreads();
    s1 = 0.f; s2 = 0.f;
    #pragma unroll
    for (int u = 0; u < 8; ++u) { s1 += r1[u]; s2 += r2[u]; }
    const float mu = s1 * (1.0f / 512.0f);
    const float rstd = rsqrtf(s2 * (1.0f / 512.0f) - mu * mu + 1e-5f);
    tsh[tid] = gelu_exact((acc - mu) * rstd * ln_g[tid] + ln_b[tid]);
    __syncthreads();

    // stage B: gv col (tid&255), split K over two halves of the block
    {
        const int col = tid & 255, half = tid >> 8;
        float g = 0.f;
        const float* wcol = Wg2 + (size_t)(half * 256) * C_ + col;
        #pragma unroll 8
        for (int j = 0; j < 256; ++j)
            g += tsh[half * 256 + j] * wcol[(size_t)j * C_];
        part2[half][col] = g;
    }
    __syncthreads();
    if (tid < C_) gvs[tid] = part2[0][tid] + part2[1][tid] + bg2[tid];
    __syncthreads();

    // stage C: vg rows tile*32..tile*32+31  (32 rows x 16 lanes, float4)
    const int o = tid >> 4, sub = tid & 15;
    const float4* gv4 = (const float4*)gvs + sub * 4;
    {
        const float4* wrow = (const float4*)(Wv + (size_t)(tile * 32 + o) * C_) + sub * 4;
        float a = 0.f;
        #pragma unroll
        for (int k4 = 0; k4 < 4; ++k4) {
            float4 w4 = wrow[k4], g4 = gv4[k4];
            a += w4.x * g4.x + w4.y * g4.y + w4.z * g4.z + w4.w * g4.w;
        }
        a += __shfl_xor(a, 1);
        a += __shfl_xor(a, 2);
        a += __shfl_xor(a, 4);
        a += __shfl_xor(a, 8);
        if (sub == 0) ws[WS_VG + b * C_ + tile * 32 + o] = a;
    }

    if (tile == 0) {
        // kg[d] = Wk[d,:]·gv  (same 32x16 decomposition)
        const float4* wrow = (const float4*)(Wk + (size_t)o * C_) + sub * 4;
        float a = 0.f;
        #pragma unroll
        for (int k4 = 0; k4 < 4; ++k4) {
            float4 w4 = wrow[k4], g4 = gv4[k4];
            a += w4.x * g4.x + w4.y * g4.y + w4.z * g4.z + w4.w * g4.w;
        }
        a += __shfl_xor(a, 1);
        a += __shfl_xor(a, 2);
        a += __shfl_xor(a, 4);
        a += __shfl_xor(a, 8);
        if (sub == 0) kg[o] = a;
        __syncthreads();
        if (tid < C_) {
            float w = 0.f;
            #pragma unroll
            for (int d = 0; d < DK_; ++d) w += kg[d] * Wq[(size_t)d * C_ + tid];
            ws[WS_WQ + b * C_ + tid] = w;
        }
        if (tid == 0) {
            float q = 0.f;
            #pragma unroll
            for (int d = 0; d < DK_; ++d) q += kg[d] * bq[d];
            ws[WS_QB + b] = q;
        }
    }
}

// One block = (b, 32-pixel tile). Loads the img tile ONCE into LDS, computes
// a -> s, then writes out = img + gamma*(vg*s + bv) for all 256 channels.
__global__ __launch_bounds__(256) void k_fused(
    const float* __restrict__ img, const float* __restrict__ l,
    const float* __restrict__ bv,  const float* __restrict__ gamma,
    const float* __restrict__ ws,  float* __restrict__ out)
{
    const int blk = blockIdx.x;          // 576 = 8 b * 72 tiles
    const int b = blk / 72;
    const int i0 = (blk % 72) * 32;
    const int tid = threadIdx.x;

    __shared__ float lsh[HW_];
    __shared__ float tile[C_][32];       // [chan][pix], bank = pix -> 2-way max
    __shared__ float wq[C_], vgb[C_], bvs[C_];
    __shared__ float part[8][32];
    __shared__ float aa[32], ss[32];
    __shared__ float redmn[4], redmx[4];

    wq[tid]  = ws[WS_WQ + b * C_ + tid];
    vgb[tid] = ws[WS_VG + b * C_ + tid];
    bvs[tid] = bv[tid];
    float mn = 1e30f, mx = -1e30f;
    #pragma unroll
    for (int j = tid; j < HW_; j += 256) {
        float v = l[j];
        lsh[j] = v;
        mn = fminf(mn, v); mx = fmaxf(mx, v);
    }
    for (int o = 32; o; o >>= 1) {
        mn = fminf(mn, __shfl_down(mn, o));
        mx = fmaxf(mx, __shfl_down(mx, o));
    }
    if ((tid & 63) == 0) { redmn[tid >> 6] = mn; redmx[tid >> 6] = mx; }
    __syncthreads();
    const float lmin = fminf(fminf(redmn[0], redmn[1]), fminf(redmn[2], redmn[3]));
    const float lmax = fmaxf(fmaxf(redmx[0], redmx[1]), fmaxf(redmx[2], redmx[3]));

    // phase 1: load img tile -> LDS, partial dot with wq
    const int pix = tid & 31, sub = tid >> 5;    // 8 chan-groups x 32 pixels
    {
        const float* x = img + ((size_t)b * C_ + sub * 32) * HW_ + i0 + pix;
        float acc = 0.f;
        #pragma unroll 8
        for (int k = 0; k < 32; ++k) {
            float v = x[(size_t)k * HW_];
            tile[sub * 32 + k][pix] = v;
            acc += wq[sub * 32 + k] * v;
        }
        part[sub][pix] = acc;
    }
    __syncthreads();
    if (tid < 32) {
        float a = ws[WS_QB + b];
        #pragma unroll
        for (int u = 0; u < 8; ++u) a += part[u][tid];
        aa[tid] = a;
    }
    __syncthreads();

    // phase 2: s[pix] = sum_j l[j] e(j) / sum_j e(j),  e = exp(a*l[j]-mx)
    {
        const int spix = tid >> 3, ssub = tid & 7;   // 32 pixels x 8 lanes
        const float m = aa[spix];
        const float mxv = (m >= 0.f) ? m * lmax : m * lmin;
        float se = 0.f, sle = 0.f;
        #pragma unroll 4
        for (int j = ssub; j < HW_; j += 8) {
            float lj = lsh[j];
            float e = __expf(m * lj - mxv);
            se += e;
            sle += e * lj;
        }
        se += __shfl_xor(se, 1);  sle += __shfl_xor(sle, 1);
        se += __shfl_xor(se, 2);  sle += __shfl_xor(sle, 2);
        se += __shfl_xor(se, 4);  sle += __shfl_xor(sle, 4);
        if (ssub == 0) ss[spix] = sle / se;
    }
    __syncthreads();

    // phase 3: out = tile + g*(vg*s + bv), coalesced 128B/half-wave writes
    {
        const float g = gamma[0];
        const float s = ss[pix];
        float* o = out + ((size_t)b * C_ + sub * 32) * HW_ + i0 + pix;
        #pragma unroll 8
        for (int k = 0; k < 32; ++k) {
            const int c = sub * 32 + k;
            o[(size_t)k * HW_] = tile[c][pix] + g * (vgb[c] * s + bvs[c]);
        }
    }
}

extern "C" void kernel_launch(void* const* d_in, const int* in_sizes, int n_in,
                              void* d_out, int out_size, void* d_ws, size_t ws_size,
                              hipStream_t stream) {
    const float* img   = (const float*)d_in[0];
    const float* text  = (const float*)d_in[1];
    const float* l     = (const float*)d_in[2];
    const float* Wg1   = (const float*)d_in[3];
    const float* bg1   = (const float*)d_in[4];
    const float* ln_g  = (const float*)d_in[5];
    const float* ln_b  = (const float*)d_in[6];
    const float* Wg2   = (const float*)d_in[7];
    const float* bg2   = (const float*)d_in[8];
    const float* Wq    = (const float*)d_in[9];
    const float* bq    = (const float*)d_in[10];
    const float* Wk    = (const float*)d_in[11];
    // bk (d_in[12]) cancels in the softmax — unused
    const float* Wv    = (const float*)d_in[13];
    const float* bv    = (const float*)d_in[14];
    const float* gamma = (const float*)d_in[15];
    float* out = (float*)d_out;
    float* ws  = (float*)d_ws;

    k_prep<<<64, 512, 0, stream>>>(text, Wg1, bg1, ln_g, ln_b, Wg2, bg2,
                                   Wq, bq, Wk, Wv, ws);
    k_fused<<<576, 256, 0, stream>>>(img, l, bv, gamma, ws, out);
}